// Round 1
// baseline (75.316 us; speedup 1.0000x reference)
//
#include <hip/hip_runtime.h>

// Single fused kernel. The grid-wide scalar lse = log(sum(exp(W))) is cheap
// enough (T = 43745) that every block recomputes it redundantly:
//   - 512 blocks x 175 KB of W reads = ~90 MB, L2-resident after warmup
//   - 512 x 43745 = 22.4M v_exp_f32 chip-wide (~1 us)
// This removes the previous partial-sum kernel, its launch, the inter-kernel
// dependency, and the workspace round-trip entirely. No inter-block
// communication -> safe under undefined dispatch order / XCD non-coherence.
//
// Phase 2: block handles 16 rows (4 per wave). Each wave prefetches its 4
// rows (independent coalesced loads), builds 4 ballots, then lanes 0..3
// compute the 4 combinatorial ranks in parallel (table = all popcount<=3
// 64-bit vectors, popcount-major, lexicographic combos within popcount).
__global__ __launch_bounds__(256) void fused_rank_kernel(
        const int* __restrict__ x,
        const float* __restrict__ W, int T,
        float* __restrict__ out, int batch) {
    __shared__ float red[4];
    __shared__ float s_lse;
    const int tid  = threadIdx.x;
    const int lane = tid & 63;
    const int wave = tid >> 6;

    // ---- Phase 1: block-local sum(exp(W)) over all T, float4-vectorized ----
    float s = 0.0f;
    const int T4 = T >> 2;
    const float4* __restrict__ W4 = (const float4*)W;
    for (int i = tid; i < T4; i += 256) {
        const float4 v = W4[i];
        s += __expf(v.x) + __expf(v.y) + __expf(v.z) + __expf(v.w);
    }
    for (int i = (T4 << 2) + tid; i < T; i += 256)
        s += __expf(W[i]);
    #pragma unroll
    for (int off = 32; off > 0; off >>= 1) s += __shfl_down(s, off, 64);
    if (lane == 0) red[wave] = s;
    __syncthreads();
    if (tid == 0) s_lse = __logf(red[0] + red[1] + red[2] + red[3]);
    __syncthreads();
    const float lse = s_lse;

    // ---- Phase 2: 4 rows per wave, prefetched ----
    const int row0 = blockIdx.x * 16 + wave * 4;
    int v0 = 0, v1 = 0, v2 = 0, v3 = 0;
    if (row0 + 0 < batch) v0 = x[(size_t)(row0 + 0) * 64 + lane];
    if (row0 + 1 < batch) v1 = x[(size_t)(row0 + 1) * 64 + lane];
    if (row0 + 2 < batch) v2 = x[(size_t)(row0 + 2) * 64 + lane];
    if (row0 + 3 < batch) v3 = x[(size_t)(row0 + 3) * 64 + lane];
    // ballots are convergent: all lanes participate
    const unsigned long long m0 = __ballot(v0 != 0);
    const unsigned long long m1 = __ballot(v1 != 0);
    const unsigned long long m2 = __ballot(v2 != 0);
    const unsigned long long m3 = __ballot(v3 != 0);

    if (lane < 4) {
        const int row = row0 + lane;
        if (row < batch) {
            // uniform scalar select (no dynamic register indexing -> no scratch)
            const unsigned long long mask =
                (lane == 0) ? m0 : (lane == 1) ? m1 : (lane == 2) ? m2 : m3;
            const int m = __popcll(mask);
            int idx;
            if (m == 0) {
                idx = 0;
            } else {
                unsigned long long t = mask;
                const int a = __builtin_ctzll(t); t &= t - 1;
                if (m == 1) {
                    idx = 1 + a;
                } else {
                    const int b = __builtin_ctzll(t); t &= t - 1;
                    if (m == 2) {
                        // 65 + sum_{j<a} C(63-j,1) + (b-a-1)
                        idx = 65 + ((4032 - (63 - a) * (64 - a)) >> 1) + (b - a - 1);
                    } else {
                        const int c = __builtin_ctzll(t);
                        // base 1 + 64 + 2016 = 2081
                        const int s1 = 41664 - ((64 - a) * (63 - a) * (62 - a)) / 6; // sum_{j<a} C(63-j,2)
                        const int s2 = ((62 - a) * (63 - a) - (63 - b) * (64 - b)) >> 1; // sum_{a<j<b} C(63-j,1)
                        idx = 2081 + s1 + s2 + (c - b - 1);
                    }
                }
            }
            out[row] = W[idx] - lse;
        }
    }
}

extern "C" void kernel_launch(void* const* d_in, const int* in_sizes, int n_in,
                              void* d_out, int out_size, void* d_ws, size_t ws_size,
                              hipStream_t stream) {
    const int*   x = (const int*)d_in[0];     // (B, 64) int32
    // d_in[1] = table — unused (structure known in closed form)
    const float* W = (const float*)d_in[2];   // (T,) float32
    float* out     = (float*)d_out;           // (B,) float32
    (void)d_ws; (void)ws_size;                // workspace no longer needed

    const int T = in_sizes[2];                // 43745
    const int B = in_sizes[0] / 64;           // 8192

    const int blocks = (B + 15) / 16;         // 16 rows per block -> 512 blocks
    fused_rank_kernel<<<blocks, 256, 0, stream>>>(x, W, T, out, B);
}